// Round 3
// baseline (818.970 us; speedup 1.0000x reference)
//
#include <hip/hip_runtime.h>
#include <stdint.h>

// CascadeAttention decode, MI355X (gfx950), fp32.
//
// R5: latency -> bandwidth conversion.
//  Post-mortem R4: timed iter = harness ws-fill(267us, fixed) + fused(295) +
//  merge(~168). fused is latency-bound (29% BW, 13% VALU): register-staged
//  seq loads keep only ~4KB/CU in flight vs 22KB needed (Little's law) ->
//  predicts ~29% BW. Fix: seq path stages K/V via async global_load_lds
//  (64KB/block in flight, zero VGPR cost). merge was a serial-chain latency
//  bind (208 GB/s) -> batched 8-wide loads + 1024 blocks.
//
//  KA fused_kernel : 6656 blocks = 512 l0 + 6144 seq, 1:12 interleave.
//     l0 path (verbatim R4): stages 4 pages K/V h-slice to LDS via regs
//       (XOR-swizzled), computes partials for all 32 b. src = chunk 0..63.
//     seq path: (b, h, 4-page tile): 512 thr issue 8x global_load_lds(16B)
//       each -> 64KB staged (LDS linear dest, XOR swizzle applied to the
//       GLOBAL source address - same involution). Waves 0-3: g=w, single
//       64-token tile softmax from LDS, q via wave-uniform s_loads, write
//       complete partial. src = 64 + tile(0..23). kNSrc = 88.
//  KB merge_kernel : 1024 blocks x 128 thr, (b,h,g); scales precomputed in
//     LDS; numer loop batched 8 loads -> MLP 8x.
// ws = 88 x [32][8][4][128] fp32 + m/l = ~47 MB. Fallback: proven R2 single
// kernel if ws too small.

namespace {
constexpr int kG = 4, kD = 128;
constexpr float kQS = 0.08838834764831845f * 1.4426950408889634f; // scale*log2e
constexpr int kNChunk = 64;   // L0: 64 groups x 4 pages
constexpr int kNTile = 24;    // seq tiles (4 pages) per (b,h)
constexpr int kNSrc = kNChunk + kNTile;               // 88
constexpr size_t kOParts = (size_t)kNSrc * 32 * 8 * 4 * 128;   // o floats
constexpr size_t kMLB = kOParts;                               // m/l base
constexpr size_t kWsFloats = kOParts + (size_t)kNSrc * 32 * 8 * 4 * 2;
// kv strides (floats): page 32768, K->V 16384, token 1024, kvh 128
}

__device__ __forceinline__ float wave_max(float v) {
#pragma unroll
    for (int off = 1; off < 64; off <<= 1) v = fmaxf(v, __shfl_xor(v, off));
    return v;
}
__device__ __forceinline__ float wave_sum(float v) {
#pragma unroll
    for (int off = 1; off < 64; off <<= 1) v += __shfl_xor(v, off);
    return v;
}
// 16B-slot swizzles (32 slots per 128-float row) for conflict-free LDS.
__device__ __forceinline__ int kslot(int s, int t) { return s ^ (t & 31); }
__device__ __forceinline__ int vslot(int s, int t) {
    return s ^ (((t << 1) & 31) | ((t >> 4) & 1));
}
// async 16B global->LDS (wave-uniform LDS base + lane*16, per-lane global)
__device__ __forceinline__ void gll16(const float* gp, float* lp) {
    __builtin_amdgcn_global_load_lds(
        (const __attribute__((address_space(1))) void*)gp,
        (__attribute__((address_space(3))) void*)lp, 16, 0, 0);
}

// ---------------- KA: fused l0 + seq partials ------------------------------
__global__ __launch_bounds__(512, 2)
void fused_kernel(const float* __restrict__ q, const float* __restrict__ kv,
                  const int* __restrict__ sp0, const int* __restrict__ sp1,
                  const int* __restrict__ sp2, float* __restrict__ ws)
{
    __shared__ __align__(16) float smem[16384];   // 64 KB: K then V (8192 ea)
    __shared__ int pgs[4];

    const int bid = blockIdx.x;
    const int tid = threadIdx.x;
    const int w = tid >> 6, lane = tid & 63;
    const int ts = lane >> 4, dg = lane & 15;
    const int l0id = bid / 13;                    // 6656 = 13 * 512

    if (bid % 13 == 0) {
        // ================= L0 path (verbatim R4): shared prefix ============
        const int h = l0id & 7, c4 = l0id >> 3;   // 64 groups x 8 h
        if (tid < 4) pgs[tid] = sp0[c4 * 4 + tid];
        __syncthreads();
        {   // stage 64 tokens of K and V (64 KB), swizzled; once per block
            const int t = tid >> 3;               // 0..63
            const int sg = (tid & 7) * 4;
            const int pg = pgs[t >> 4];
            const float* gk = kv + (size_t)pg * 32768u + (size_t)(t & 15) * 1024u + h * 128;
#pragma unroll
            for (int j = 0; j < 4; ++j) {
                const int s = sg + j;
                *(float4*)&smem[t * 128 + (kslot(s, t) << 2)] =
                    *(const float4*)(gk + s * 4);
                *(float4*)&smem[8192 + t * 128 + (vslot(s, t) << 2)] =
                    *(const float4*)(gk + 16384 + s * 4);
            }
        }
        __syncthreads();

        const int wq = __builtin_amdgcn_readfirstlane(w);
        for (int pass = 0; pass < 4; ++pass) {
            const int b = wq * 4 + pass;          // wave-uniform row batch
            const float* qb = q + (size_t)b * 4096 + h * 512;  // uniform addr
            float s[4] = {0.f, 0.f, 0.f, 0.f};
#pragma unroll
            for (int c = 0; c < 16; ++c) {
                float4 ka = *(const float4*)&smem[lane * 128 + (kslot(2 * c, lane) << 2)];
                float4 kb = *(const float4*)&smem[lane * 128 + (kslot(2 * c + 1, lane) << 2)];
#pragma unroll
                for (int g = 0; g < 4; ++g) {
                    float4 qa = *(const float4*)(qb + g * 128 + c * 8);
                    float4 q2 = *(const float4*)(qb + g * 128 + c * 8 + 4);
                    s[g] += ka.x * qa.x + ka.y * qa.y + ka.z * qa.z + ka.w * qa.w
                          + kb.x * q2.x + kb.y * q2.y + kb.z * q2.z + kb.w * q2.w;
                }
            }
            float m[4], p[4], l[4], acc[4][8];
#pragma unroll
            for (int g = 0; g < 4; ++g) {
                s[g] *= kQS;
                m[g] = wave_max(s[g]);
                p[g] = exp2f(s[g] - m[g]);
                l[g] = wave_sum(p[g]);
#pragma unroll
                for (int e = 0; e < 8; ++e) acc[g][e] = 0.f;
            }
#pragma unroll
            for (int j = 0; j < 16; ++j) {
                const int t = ts * 16 + j;
                float4 va = *(const float4*)&smem[8192 + t * 128 + (vslot(2 * dg, t) << 2)];
                float4 vb = *(const float4*)&smem[8192 + t * 128 + (vslot(2 * dg + 1, t) << 2)];
#pragma unroll
                for (int g = 0; g < 4; ++g) {
                    float pj = __shfl(p[g], t);
                    acc[g][0] = fmaf(pj, va.x, acc[g][0]);
                    acc[g][1] = fmaf(pj, va.y, acc[g][1]);
                    acc[g][2] = fmaf(pj, va.z, acc[g][2]);
                    acc[g][3] = fmaf(pj, va.w, acc[g][3]);
                    acc[g][4] = fmaf(pj, vb.x, acc[g][4]);
                    acc[g][5] = fmaf(pj, vb.y, acc[g][5]);
                    acc[g][6] = fmaf(pj, vb.z, acc[g][6]);
                    acc[g][7] = fmaf(pj, vb.w, acc[g][7]);
                }
            }
#pragma unroll
            for (int g = 0; g < 4; ++g)
#pragma unroll
                for (int e = 0; e < 8; ++e) {
                    float v = acc[g][e];
                    v += __shfl_xor(v, 16);
                    v += __shfl_xor(v, 32);
                    acc[g][e] = v;
                }
            if (lane < 16) {
                const size_t ob = ((((size_t)c4 * 32 + b) * 8 + h) * 4) * 128 + lane * 8;
#pragma unroll
                for (int g = 0; g < 4; ++g) {
                    *(float4*)&ws[ob + (size_t)g * 128] =
                        make_float4(acc[g][0], acc[g][1], acc[g][2], acc[g][3]);
                    *(float4*)&ws[ob + (size_t)g * 128 + 4] =
                        make_float4(acc[g][4], acc[g][5], acc[g][6], acc[g][7]);
                }
            }
            if (lane == 0) {
                const size_t idx = (((size_t)c4 * 32 + b) * 8 + h) * 4;
#pragma unroll
                for (int g = 0; g < 4; ++g) {
                    ws[kMLB + 2 * (idx + g)] = m[g];
                    ws[kMLB + 2 * (idx + g) + 1] = l[g];
                }
            }
        }
    } else {
        // ================= seq path: async-staged 4-page tile ==============
        const int sid = bid - l0id - 1;           // 0..6143
        const int b = sid / 192;                  // 8h * 24t = 192
        const int h = (sid / 24) & 7;
        const int tle = sid % 24;
        const int wq = __builtin_amdgcn_readfirstlane(w);

        // this wave's 8 rows (wq*8..+7) lie in ONE page: j = tle*4 + (wq>>1)
        const int jw = tle * 4 + (wq >> 1);
        const int pgw = (jw < 64) ? sp1[b * 64 + jw] : sp2[b * 32 + (jw - 64)];
        const size_t poff = (size_t)pgw * 32768u;

        {   // stage: 4 K-gll + 4 V-gll per thread; LDS linear, source XORed
            const int sl = lane & 31;             // 16B slot within row
            const int rl = lane >> 5;             // row within pair
#pragma unroll
            for (int i = 0; i < 4; ++i) {
                const int r = wq * 8 + i * 2 + rl;      // token row 0..63
                const float* gk = kv + poff + (size_t)(r & 15) * 1024u + h * 128;
                gll16(gk + ((sl ^ (r & 31)) << 2),
                      &smem[wq * 1024 + i * 256]);
                const int vm = ((r << 1) & 31) | ((r >> 4) & 1);
                gll16(gk + 16384 + ((sl ^ vm) << 2),
                      &smem[8192 + wq * 1024 + i * 256]);
            }
        }
        __syncthreads();                           // drains vmcnt, LDS ready

        if (wq < 4) {
            const int g = wq;
            const float* qb = q + (size_t)b * 4096 + h * 512 + g * 128; // uniform
            float s = 0.f;
#pragma unroll
            for (int c = 0; c < 16; ++c) {
                float4 ka = *(const float4*)&smem[lane * 128 + (kslot(2 * c, lane) << 2)];
                float4 kb = *(const float4*)&smem[lane * 128 + (kslot(2 * c + 1, lane) << 2)];
                float4 qa = *(const float4*)(qb + c * 8);
                float4 q2 = *(const float4*)(qb + c * 8 + 4);
                s += ka.x * qa.x + ka.y * qa.y + ka.z * qa.z + ka.w * qa.w
                   + kb.x * q2.x + kb.y * q2.y + kb.z * q2.z + kb.w * q2.w;
            }
            s *= kQS;
            const float m = wave_max(s);
            const float p = exp2f(s - m);
            const float l = wave_sum(p);
            float acc[8];
#pragma unroll
            for (int e = 0; e < 8; ++e) acc[e] = 0.f;
#pragma unroll
            for (int j = 0; j < 16; ++j) {
                const int t = ts * 16 + j;
                float4 va = *(const float4*)&smem[8192 + t * 128 + (vslot(2 * dg, t) << 2)];
                float4 vb = *(const float4*)&smem[8192 + t * 128 + (vslot(2 * dg + 1, t) << 2)];
                const float pj = __shfl(p, t);
                acc[0] = fmaf(pj, va.x, acc[0]);
                acc[1] = fmaf(pj, va.y, acc[1]);
                acc[2] = fmaf(pj, va.z, acc[2]);
                acc[3] = fmaf(pj, va.w, acc[3]);
                acc[4] = fmaf(pj, vb.x, acc[4]);
                acc[5] = fmaf(pj, vb.y, acc[5]);
                acc[6] = fmaf(pj, vb.z, acc[6]);
                acc[7] = fmaf(pj, vb.w, acc[7]);
            }
#pragma unroll
            for (int e = 0; e < 8; ++e) {
                float v = acc[e];
                v += __shfl_xor(v, 16);
                v += __shfl_xor(v, 32);
                acc[e] = v;
            }
            const size_t src = (size_t)(kNChunk + tle);
            if (lane < 16) {
                const size_t ob = (((src * 32 + b) * 8 + h) * 4 + g) * 128 + lane * 8;
                *(float4*)&ws[ob]     = make_float4(acc[0], acc[1], acc[2], acc[3]);
                *(float4*)&ws[ob + 4] = make_float4(acc[4], acc[5], acc[6], acc[7]);
            }
            if (lane == 0) {
                const size_t idx = ((src * 32 + b) * 8 + h) * 4 + g;
                ws[kMLB + 2 * idx] = m;
                ws[kMLB + 2 * idx + 1] = l;
            }
        }
    }
}

// ---------------- KB: final merge of 88 partials (batched MLP) -------------
__global__ __launch_bounds__(128, 8)
void merge_kernel(const float* __restrict__ ws, float* __restrict__ out)
{
    __shared__ float sm[kNSrc], sls[kNSrc], sc[kNSrc];
    const int bid = blockIdx.x;                   // 1024 = b(32) x h(8) x g(4)
    const int b = bid >> 5, h = (bid >> 2) & 7, g = bid & 3;
    const int tid = threadIdx.x;                  // d 0..127
    if (tid < kNSrc) {
        const size_t idx = (((size_t)tid * 32 + b) * 8 + h) * 4 + g;
        sm[tid]  = ws[kMLB + 2 * idx];
        sls[tid] = ws[kMLB + 2 * idx + 1];
    }
    __syncthreads();
    float mstar = -1e30f;
#pragma unroll
    for (int s = 0; s < kNSrc; ++s) mstar = fmaxf(mstar, sm[s]);   // broadcast
    if (tid < kNSrc) sc[tid] = exp2f(sm[tid] - mstar);
    __syncthreads();
    float denom = 0.f;
#pragma unroll
    for (int s = 0; s < kNSrc; ++s) denom = fmaf(sc[s], sls[s], denom);
    const size_t base = ((((size_t)b * 8 + h) * 4 + g) * 128) + tid;
    float numer = 0.f;
#pragma unroll 1
    for (int s0 = 0; s0 < kNSrc; s0 += 8) {       // 88 = 11 x 8
        float v[8];
#pragma unroll
        for (int k = 0; k < 8; ++k)
            v[k] = ws[base + (size_t)(s0 + k) * 131072u];
#pragma unroll
        for (int k = 0; k < 8; ++k)
            numer = fmaf(sc[s0 + k], v[k], numer);
    }
    out[(size_t)b * 4096 + h * 512 + g * 128 + tid] = numer / denom;
}

// ---------------- fallback: proven R2 single kernel (fp32) -----------------
__global__ __launch_bounds__(512, 2)
void fallback_kernel(const float* __restrict__ q, const float* __restrict__ kv,
                     const int* __restrict__ sp0, const int* __restrict__ sp1,
                     const int* __restrict__ sp2, float* __restrict__ out)
{
    __shared__ __align__(16) float qs[kG * kD];
    __shared__ int plist[352];
    __shared__ __align__(16) float wacc[8][kG * kD];
    __shared__ float wm[8][kG], wl[8][kG];
    const int b = blockIdx.x >> 3, h = blockIdx.x & 7;
    const int tid = threadIdx.x;
    {
        const int g = tid >> 7, d = tid & 127;
        qs[g * 128 + d] = q[(size_t)b * 4096 + h * 512 + g * 128 + d] * kQS;
    }
    if (tid < 352) {
        int pg;
        if (tid < 256)      pg = sp0[tid];
        else if (tid < 320) pg = sp1[b * 64 + (tid - 256)];
        else                pg = sp2[b * 32 + (tid - 320)];
        plist[tid] = pg;
    }
    __syncthreads();
    const int w = tid >> 6, lane = tid & 63;
    const int ts = lane >> 4, dg = lane & 15;
    const float4* qv4 = (const float4*)qs;
    float m[kG], l[kG], acc[kG][8];
#pragma unroll
    for (int g = 0; g < kG; ++g) {
        m[g] = -1e30f; l[g] = 0.f;
#pragma unroll
        for (int e = 0; e < 8; ++e) acc[g][e] = 0.f;
    }
    for (int tile = 0; tile < 11; ++tile) {
        const int page = plist[w * 44 + tile * 4 + ts];
        const size_t poff = (size_t)page * 32768u;
        const float* Kp = kv + poff + (size_t)(lane & 15) * 1024u + h * 128;
        const float* Vp = kv + poff + 16384u + h * 128 + dg * 8;
        float s[kG] = {0.f, 0.f, 0.f, 0.f};
#pragma unroll
        for (int c = 0; c < 16; ++c) {
            float4 ka = *(const float4*)(Kp + c * 8);
            float4 kb = *(const float4*)(Kp + c * 8 + 4);
#pragma unroll
            for (int g = 0; g < kG; ++g) {
                float4 qa = qv4[g * 32 + c * 2];
                float4 qb = qv4[g * 32 + c * 2 + 1];
                s[g] += ka.x * qa.x + ka.y * qa.y + ka.z * qa.z + ka.w * qa.w
                      + kb.x * qb.x + kb.y * qb.y + kb.z * qb.z + kb.w * qb.w;
            }
        }
        float p[kG];
#pragma unroll
        for (int g = 0; g < kG; ++g) {
            float mt = wave_max(s[g]);
            float mn = fmaxf(m[g], mt);
            float alpha = exp2f(m[g] - mn);
            p[g] = exp2f(s[g] - mn);
            m[g] = mn;
            l[g] = l[g] * alpha + wave_sum(p[g]);
#pragma unroll
            for (int e = 0; e < 8; ++e) acc[g][e] *= alpha;
        }
#pragma unroll
        for (int j = 0; j < 16; ++j) {
            const int t = ts * 16 + j;
            float4 va = *(const float4*)(Vp + (size_t)j * 1024u);
            float4 vb = *(const float4*)(Vp + (size_t)j * 1024u + 4);
#pragma unroll
            for (int g = 0; g < kG; ++g) {
                float pj = __shfl(p[g], t);
                acc[g][0] = fmaf(pj, va.x, acc[g][0]);
                acc[g][1] = fmaf(pj, va.y, acc[g][1]);
                acc[g][2] = fmaf(pj, va.z, acc[g][2]);
                acc[g][3] = fmaf(pj, va.w, acc[g][3]);
                acc[g][4] = fmaf(pj, vb.x, acc[g][4]);
                acc[g][5] = fmaf(pj, vb.y, acc[g][5]);
                acc[g][6] = fmaf(pj, vb.z, acc[g][6]);
                acc[g][7] = fmaf(pj, vb.w, acc[g][7]);
            }
        }
    }
#pragma unroll
    for (int g = 0; g < kG; ++g)
#pragma unroll
        for (int e = 0; e < 8; ++e) {
            float v = acc[g][e];
            v += __shfl_xor(v, 16);
            v += __shfl_xor(v, 32);
            acc[g][e] = v;
        }
    if (lane < 16) {
#pragma unroll
        for (int g = 0; g < kG; ++g) {
            *(float4*)&wacc[w][g * 128 + dg * 8]     = make_float4(acc[g][0], acc[g][1], acc[g][2], acc[g][3]);
            *(float4*)&wacc[w][g * 128 + dg * 8 + 4] = make_float4(acc[g][4], acc[g][5], acc[g][6], acc[g][7]);
        }
        if (lane == 0)
#pragma unroll
            for (int g = 0; g < kG; ++g) { wm[w][g] = m[g]; wl[w][g] = l[g]; }
    }
    __syncthreads();
    {
        const int g = tid >> 7, d = tid & 127;
        float mstar = wm[0][g];
#pragma unroll
        for (int ww = 1; ww < 8; ++ww) mstar = fmaxf(mstar, wm[ww][g]);
        float numer = 0.f, denom = 0.f;
#pragma unroll
        for (int ww = 0; ww < 8; ++ww) {
            float sc = exp2f(wm[ww][g] - mstar);
            denom = fmaf(sc, wl[ww][g], denom);
            numer = fmaf(sc, wacc[ww][g * 128 + d], numer);
        }
        out[(size_t)b * 4096 + h * 512 + g * 128 + d] = numer / denom;
    }
}

extern "C" void kernel_launch(void* const* d_in, const int* in_sizes, int n_in,
                              void* d_out, int out_size, void* d_ws, size_t ws_size,
                              hipStream_t stream) {
    const float* q  = (const float*)d_in[0];
    const float* kv = (const float*)d_in[1];
    const int* sp0 = (const int*)d_in[2];
    const int* sp1 = (const int*)d_in[3];
    const int* sp2 = (const int*)d_in[4];
    float* out = (float*)d_out;
    float* ws = (float*)d_ws;
    if (ws_size >= kWsFloats * sizeof(float)) {
        hipLaunchKernelGGL(fused_kernel, dim3(6656), dim3(512), 0, stream,
                           q, kv, sp0, sp1, sp2, ws);
        hipLaunchKernelGGL(merge_kernel, dim3(1024), dim3(128), 0, stream, ws, out);
    } else {
        hipLaunchKernelGGL(fallback_kernel, dim3(256), dim3(512), 0, stream,
                           q, kv, sp0, sp1, sp2, out);
    }
}

// Round 4
// 780.483 us; speedup vs baseline: 1.0493x; 1.0493x over previous
//
#include <hip/hip_runtime.h>
#include <stdint.h>

// CascadeAttention decode, MI355X (gfx950), fp32.
//
// R6: split kernels + deep register batching.
//  R5 post-mortem: gll16 stage->drain(vmcnt0)->compute serialized memory and
//  compute (BW 23%, half the waves idle in compute). R4's register path was
//  better (29%) but Little's-law bound (~6 loads in flight). Fusion also let
//  l0's 64KB-LDS blocks (27us each) starve seq blocks at 2 blocks/CU.
//  R6: three sequential dispatches:
//   K1 l0_kernel  : R4 l0 path verbatim, standalone. 512 blocks x 512 thr,
//                   64KB LDS, src 0..63.
//   K2 seq_kernel : 1536 blocks x 256 thr (LB(256,4)), NO LDS, no barriers.
//                   wave = one 4-page tile (6144 waves = 32b x 8h x 24t).
//                   K: hand-unrolled double-buffered 8xfloat4 batches
//                   (8 loads/lane in flight). V batch-0 issued BEFORE softmax.
//                   Direct per-wave partial write. src 64..87.
//   K3 merge_kernel: R5's batched LSE merge, 1024 x 128.
// ws = 88 x [32][8][4][128] fp32 + m/l = ~47 MB. Fallback: proven R2 single
// kernel if ws too small.

namespace {
constexpr int kG = 4, kD = 128;
constexpr float kQS = 0.08838834764831845f * 1.4426950408889634f; // scale*log2e
constexpr int kNChunk = 64;   // L0: 64 groups x 4 pages
constexpr int kNTile = 24;    // seq tiles (4 pages) per (b,h)
constexpr int kNSrc = kNChunk + kNTile;               // 88
constexpr size_t kOParts = (size_t)kNSrc * 32 * 8 * 4 * 128;   // o floats
constexpr size_t kMLB = kOParts;                               // m/l base
constexpr size_t kWsFloats = kOParts + (size_t)kNSrc * 32 * 8 * 4 * 2;
// kv strides (floats): page 32768, K->V 16384, token 1024, kvh 128
}

__device__ __forceinline__ float wave_max(float v) {
#pragma unroll
    for (int off = 1; off < 64; off <<= 1) v = fmaxf(v, __shfl_xor(v, off));
    return v;
}
__device__ __forceinline__ float wave_sum(float v) {
#pragma unroll
    for (int off = 1; off < 64; off <<= 1) v += __shfl_xor(v, off);
    return v;
}
// 16B-slot swizzles (32 slots per 128-float row) for conflict-free LDS (l0).
__device__ __forceinline__ int kslot(int s, int t) { return s ^ (t & 31); }
__device__ __forceinline__ int vslot(int s, int t) {
    return s ^ (((t << 1) & 31) | ((t >> 4) & 1));
}

// ---------------- K1: shared-prefix l0 (R4 path, standalone) ---------------
__global__ __launch_bounds__(512, 2)
void l0_kernel(const float* __restrict__ q, const float* __restrict__ kv,
               const int* __restrict__ sp0, float* __restrict__ ws)
{
    __shared__ __align__(16) float smem[16384];   // 64 KB: K then V
    __shared__ int pgs[4];

    const int bid = blockIdx.x;                   // 512 = 64 groups x 8 h
    const int h = bid & 7, c4 = bid >> 3;
    const int tid = threadIdx.x;
    const int w = tid >> 6, lane = tid & 63;
    const int ts = lane >> 4, dg = lane & 15;

    if (tid < 4) pgs[tid] = sp0[c4 * 4 + tid];
    __syncthreads();
    {   // stage 64 tokens of K and V (64 KB), swizzled; once per block
        const int t = tid >> 3;                   // 0..63
        const int sg = (tid & 7) * 4;
        const int pg = pgs[t >> 4];
        const float* gk = kv + (size_t)pg * 32768u + (size_t)(t & 15) * 1024u + h * 128;
#pragma unroll
        for (int j = 0; j < 4; ++j) {
            const int s = sg + j;
            *(float4*)&smem[t * 128 + (kslot(s, t) << 2)] =
                *(const float4*)(gk + s * 4);
            *(float4*)&smem[8192 + t * 128 + (vslot(s, t) << 2)] =
                *(const float4*)(gk + 16384 + s * 4);
        }
    }
    __syncthreads();

    const int wq = __builtin_amdgcn_readfirstlane(w);
    for (int pass = 0; pass < 4; ++pass) {
        const int b = wq * 4 + pass;              // wave-uniform row batch
        const float* qb = q + (size_t)b * 4096 + h * 512;  // uniform addr
        float s[4] = {0.f, 0.f, 0.f, 0.f};
#pragma unroll
        for (int c = 0; c < 16; ++c) {
            float4 ka = *(const float4*)&smem[lane * 128 + (kslot(2 * c, lane) << 2)];
            float4 kb = *(const float4*)&smem[lane * 128 + (kslot(2 * c + 1, lane) << 2)];
#pragma unroll
            for (int g = 0; g < 4; ++g) {
                float4 qa = *(const float4*)(qb + g * 128 + c * 8);
                float4 q2 = *(const float4*)(qb + g * 128 + c * 8 + 4);
                s[g] += ka.x * qa.x + ka.y * qa.y + ka.z * qa.z + ka.w * qa.w
                      + kb.x * q2.x + kb.y * q2.y + kb.z * q2.z + kb.w * q2.w;
            }
        }
        float m[4], p[4], l[4], acc[4][8];
#pragma unroll
        for (int g = 0; g < 4; ++g) {
            s[g] *= kQS;
            m[g] = wave_max(s[g]);
            p[g] = exp2f(s[g] - m[g]);
            l[g] = wave_sum(p[g]);
#pragma unroll
            for (int e = 0; e < 8; ++e) acc[g][e] = 0.f;
        }
#pragma unroll
        for (int j = 0; j < 16; ++j) {
            const int t = ts * 16 + j;
            float4 va = *(const float4*)&smem[8192 + t * 128 + (vslot(2 * dg, t) << 2)];
            float4 vb = *(const float4*)&smem[8192 + t * 128 + (vslot(2 * dg + 1, t) << 2)];
#pragma unroll
            for (int g = 0; g < 4; ++g) {
                float pj = __shfl(p[g], t);
                acc[g][0] = fmaf(pj, va.x, acc[g][0]);
                acc[g][1] = fmaf(pj, va.y, acc[g][1]);
                acc[g][2] = fmaf(pj, va.z, acc[g][2]);
                acc[g][3] = fmaf(pj, va.w, acc[g][3]);
                acc[g][4] = fmaf(pj, vb.x, acc[g][4]);
                acc[g][5] = fmaf(pj, vb.y, acc[g][5]);
                acc[g][6] = fmaf(pj, vb.z, acc[g][6]);
                acc[g][7] = fmaf(pj, vb.w, acc[g][7]);
            }
        }
#pragma unroll
        for (int g = 0; g < 4; ++g)
#pragma unroll
            for (int e = 0; e < 8; ++e) {
                float v = acc[g][e];
                v += __shfl_xor(v, 16);
                v += __shfl_xor(v, 32);
                acc[g][e] = v;
            }
        if (lane < 16) {
            const size_t ob = ((((size_t)c4 * 32 + b) * 8 + h) * 4) * 128 + lane * 8;
#pragma unroll
            for (int g = 0; g < 4; ++g) {
                *(float4*)&ws[ob + (size_t)g * 128] =
                    make_float4(acc[g][0], acc[g][1], acc[g][2], acc[g][3]);
                *(float4*)&ws[ob + (size_t)g * 128 + 4] =
                    make_float4(acc[g][4], acc[g][5], acc[g][6], acc[g][7]);
            }
        }
        if (lane == 0) {
            const size_t idx = (((size_t)c4 * 32 + b) * 8 + h) * 4;
#pragma unroll
            for (int g = 0; g < 4; ++g) {
                ws[kMLB + 2 * (idx + g)] = m[g];
                ws[kMLB + 2 * (idx + g) + 1] = l[g];
            }
        }
    }
}

// ---------------- K2: seq levels, register-streamed, no LDS ----------------
// K-batch macros: consume 8 float4 of K (d = BB*32..+31) while next batch
// loads; all indices compile-time so arrays stay in registers.
#define K_LOAD(dst, off)                                                    \
    _Pragma("unroll")                                                       \
    for (int i = 0; i < 8; ++i) dst[i] = Kp[(off) + i];
#define K_FMA(cur, BB)                                                      \
    _Pragma("unroll")                                                       \
    for (int i = 0; i < 8; ++i) {                                           \
        float4 kk = cur[i];                                                 \
        _Pragma("unroll")                                                   \
        for (int g = 0; g < 4; ++g) {                                       \
            float4 qq = qv4[g * 32 + (BB) * 8 + i];                         \
            s[g] += kk.x * qq.x + kk.y * qq.y + kk.z * qq.z + kk.w * qq.w;  \
        }                                                                   \
    }
#define V_LOAD(dst, j0)                                                     \
    _Pragma("unroll")                                                       \
    for (int j = 0; j < 4; ++j) {                                           \
        dst[2 * j]     = Vp[((j0) + j) * 256];                              \
        dst[2 * j + 1] = Vp[((j0) + j) * 256 + 1];                          \
    }
#define V_FMA(cur, JB)                                                     \
    _Pragma("unroll")                                                       \
    for (int jj = 0; jj < 4; ++jj) {                                        \
        const int t = ts * 16 + (JB) * 4 + jj;                              \
        float4 x = cur[2 * jj], y = cur[2 * jj + 1];                        \
        _Pragma("unroll")                                                   \
        for (int g = 0; g < 4; ++g) {                                       \
            float pj = __shfl(p[g], t);                                     \
            acc[g][0] = fmaf(pj, x.x, acc[g][0]);                           \
            acc[g][1] = fmaf(pj, x.y, acc[g][1]);                           \
            acc[g][2] = fmaf(pj, x.z, acc[g][2]);                           \
            acc[g][3] = fmaf(pj, x.w, acc[g][3]);                           \
            acc[g][4] = fmaf(pj, y.x, acc[g][4]);                           \
            acc[g][5] = fmaf(pj, y.y, acc[g][5]);                           \
            acc[g][6] = fmaf(pj, y.z, acc[g][6]);                           \
            acc[g][7] = fmaf(pj, y.w, acc[g][7]);                           \
        }                                                                   \
    }

__global__ __launch_bounds__(256, 4)
void seq_kernel(const float* __restrict__ q, const float* __restrict__ kv,
                const int* __restrict__ sp1, const int* __restrict__ sp2,
                float* __restrict__ ws)
{
    const int tid = threadIdx.x;
    const int w = tid >> 6, lane = tid & 63;
    const int ts = lane >> 4, dg = lane & 15;
    // block -> (b, h, tg); wave -> tile = tg*4 + w.  1536 = 32b * 8h * 6tg
    const int bid = blockIdx.x;
    const int b  = bid / 48;
    const int h  = (bid / 6) & 7;
    const int tg = bid % 6;
    const int tile = tg * 4 + __builtin_amdgcn_readfirstlane(w);

    // lane (ts, tok=lane&15): page per quarter
    const int jw = tile * 4 + ts;
    const int pg = (jw < 64) ? sp1[b * 64 + jw] : sp2[b * 32 + (jw - 64)];
    const size_t poff = (size_t)pg * 32768u;

    const float4* Kp  = (const float4*)(kv + poff + (size_t)(lane & 15) * 1024u + (size_t)h * 128);
    const float4* qv4 = (const float4*)(q + (size_t)b * 4096 + (size_t)h * 512);  // block-uniform

    // ---- QK^T: 4 double-buffered batches of 8 float4 (8 loads in flight) --
    float4 kb0[8], kb1[8];
    float s[4] = {0.f, 0.f, 0.f, 0.f};
    K_LOAD(kb0, 0)
    K_LOAD(kb1, 8)
    K_FMA(kb0, 0)
    K_LOAD(kb0, 16)
    K_FMA(kb1, 1)
    K_LOAD(kb1, 24)
    K_FMA(kb0, 2)
    K_FMA(kb1, 3)

    // ---- issue V batch 0 BEFORE softmax (hides shuffles under HBM) -------
    const float4* Vp = (const float4*)(kv + poff + 16384u + (size_t)h * 128 + dg * 8);
    float4 v0[8], v1[8];
    V_LOAD(v0, 0)

    float m[4], p[4], l[4];
#pragma unroll
    for (int g = 0; g < 4; ++g) {
        s[g] *= kQS;
        m[g] = wave_max(s[g]);
        p[g] = exp2f(s[g] - m[g]);
        l[g] = wave_sum(p[g]);
    }
    float acc[4][8];
#pragma unroll
    for (int g = 0; g < 4; ++g)
#pragma unroll
        for (int e = 0; e < 8; ++e) acc[g][e] = 0.f;

    // ---- PV: 4 double-buffered token batches ------------------------------
    V_LOAD(v1, 4)
    V_FMA(v0, 0)
    V_LOAD(v0, 8)
    V_FMA(v1, 1)
    V_LOAD(v1, 12)
    V_FMA(v0, 2)
    V_FMA(v1, 3)

    // reduce over the 4 token-quarters; write partial (o unnormalized, m, l)
#pragma unroll
    for (int g = 0; g < 4; ++g)
#pragma unroll
        for (int e = 0; e < 8; ++e) {
            float v = acc[g][e];
            v += __shfl_xor(v, 16);
            v += __shfl_xor(v, 32);
            acc[g][e] = v;
        }
    const size_t src = (size_t)(kNChunk + tile);
    if (lane < 16) {
        const size_t ob = (((src * 32 + b) * 8 + h) * 4) * 128 + lane * 8;
#pragma unroll
        for (int g = 0; g < 4; ++g) {
            *(float4*)&ws[ob + (size_t)g * 128] =
                make_float4(acc[g][0], acc[g][1], acc[g][2], acc[g][3]);
            *(float4*)&ws[ob + (size_t)g * 128 + 4] =
                make_float4(acc[g][4], acc[g][5], acc[g][6], acc[g][7]);
        }
    }
    if (lane == 0) {
        const size_t idx = ((src * 32 + b) * 8 + h) * 4;
#pragma unroll
        for (int g = 0; g < 4; ++g) {
            ws[kMLB + 2 * (idx + g)] = m[g];
            ws[kMLB + 2 * (idx + g) + 1] = l[g];
        }
    }
}

// ---------------- K3: final merge of 88 partials (batched MLP) -------------
__global__ __launch_bounds__(128, 8)
void merge_kernel(const float* __restrict__ ws, float* __restrict__ out)
{
    __shared__ float sm[kNSrc], sls[kNSrc], sc[kNSrc];
    const int bid = blockIdx.x;                   // 1024 = b(32) x h(8) x g(4)
    const int b = bid >> 5, h = (bid >> 2) & 7, g = bid & 3;
    const int tid = threadIdx.x;                  // d 0..127
    if (tid < kNSrc) {
        const size_t idx = (((size_t)tid * 32 + b) * 8 + h) * 4 + g;
        sm[tid]  = ws[kMLB + 2 * idx];
        sls[tid] = ws[kMLB + 2 * idx + 1];
    }
    __syncthreads();
    float mstar = -1e30f;
#pragma unroll
    for (int s = 0; s < kNSrc; ++s) mstar = fmaxf(mstar, sm[s]);   // broadcast
    if (tid < kNSrc) sc[tid] = exp2f(sm[tid] - mstar);
    __syncthreads();
    float denom = 0.f;
#pragma unroll
    for (int s = 0; s < kNSrc; ++s) denom = fmaf(sc[s], sls[s], denom);
    const size_t base = ((((size_t)b * 8 + h) * 4 + g) * 128) + tid;
    float numer = 0.f;
#pragma unroll 1
    for (int s0 = 0; s0 < kNSrc; s0 += 8) {       // 88 = 11 x 8
        float v[8];
#pragma unroll
        for (int k = 0; k < 8; ++k)
            v[k] = ws[base + (size_t)(s0 + k) * 131072u];
#pragma unroll
        for (int k = 0; k < 8; ++k)
            numer = fmaf(sc[s0 + k], v[k], numer);
    }
    out[(size_t)b * 4096 + h * 512 + g * 128 + tid] = numer / denom;
}

// ---------------- fallback: proven R2 single kernel (fp32) -----------------
__global__ __launch_bounds__(512, 2)
void fallback_kernel(const float* __restrict__ q, const float* __restrict__ kv,
                     const int* __restrict__ sp0, const int* __restrict__ sp1,
                     const int* __restrict__ sp2, float* __restrict__ out)
{
    __shared__ __align__(16) float qs[kG * kD];
    __shared__ int plist[352];
    __shared__ __align__(16) float wacc[8][kG * kD];
    __shared__ float wm[8][kG], wl[8][kG];
    const int b = blockIdx.x >> 3, h = blockIdx.x & 7;
    const int tid = threadIdx.x;
    {
        const int g = tid >> 7, d = tid & 127;
        qs[g * 128 + d] = q[(size_t)b * 4096 + h * 512 + g * 128 + d] * kQS;
    }
    if (tid < 352) {
        int pg;
        if (tid < 256)      pg = sp0[tid];
        else if (tid < 320) pg = sp1[b * 64 + (tid - 256)];
        else                pg = sp2[b * 32 + (tid - 320)];
        plist[tid] = pg;
    }
    __syncthreads();
    const int w = tid >> 6, lane = tid & 63;
    const int ts = lane >> 4, dg = lane & 15;
    const float4* qv4 = (const float4*)qs;
    float m[kG], l[kG], acc[kG][8];
#pragma unroll
    for (int g = 0; g < kG; ++g) {
        m[g] = -1e30f; l[g] = 0.f;
#pragma unroll
        for (int e = 0; e < 8; ++e) acc[g][e] = 0.f;
    }
    for (int tile = 0; tile < 11; ++tile) {
        const int page = plist[w * 44 + tile * 4 + ts];
        const size_t poff = (size_t)page * 32768u;
        const float* Kp = kv + poff + (size_t)(lane & 15) * 1024u + h * 128;
        const float* Vp = kv + poff + 16384u + h * 128 + dg * 8;
        float s[kG] = {0.f, 0.f, 0.f, 0.f};
#pragma unroll
        for (int c = 0; c < 16; ++c) {
            float4 ka = *(const float4*)(Kp + c * 8);
            float4 kb = *(const float4*)(Kp + c * 8 + 4);
#pragma unroll
            for (int g = 0; g < kG; ++g) {
                float4 qa = qv4[g * 32 + c * 2];
                float4 qb = qv4[g * 32 + c * 2 + 1];
                s[g] += ka.x * qa.x + ka.y * qa.y + ka.z * qa.z + ka.w * qa.w
                      + kb.x * qb.x + kb.y * qb.y + kb.z * qb.z + kb.w * qb.w;
            }
        }
        float p[kG];
#pragma unroll
        for (int g = 0; g < kG; ++g) {
            float mt = wave_max(s[g]);
            float mn = fmaxf(m[g], mt);
            float alpha = exp2f(m[g] - mn);
            p[g] = exp2f(s[g] - mn);
            m[g] = mn;
            l[g] = l[g] * alpha + wave_sum(p[g]);
#pragma unroll
            for (int e = 0; e < 8; ++e) acc[g][e] *= alpha;
        }
#pragma unroll
        for (int j = 0; j < 16; ++j) {
            const int t = ts * 16 + j;
            float4 va = *(const float4*)(Vp + (size_t)j * 1024u);
            float4 vb = *(const float4*)(Vp + (size_t)j * 1024u + 4);
#pragma unroll
            for (int g = 0; g < kG; ++g) {
                float pj = __shfl(p[g], t);
                acc[g][0] = fmaf(pj, va.x, acc[g][0]);
                acc[g][1] = fmaf(pj, va.y, acc[g][1]);
                acc[g][2] = fmaf(pj, va.z, acc[g][2]);
                acc[g][3] = fmaf(pj, va.w, acc[g][3]);
                acc[g][4] = fmaf(pj, vb.x, acc[g][4]);
                acc[g][5] = fmaf(pj, vb.y, acc[g][5]);
                acc[g][6] = fmaf(pj, vb.z, acc[g][6]);
                acc[g][7] = fmaf(pj, vb.w, acc[g][7]);
            }
        }
    }
#pragma unroll
    for (int g = 0; g < kG; ++g)
#pragma unroll
        for (int e = 0; e < 8; ++e) {
            float v = acc[g][e];
            v += __shfl_xor(v, 16);
            v += __shfl_xor(v, 32);
            acc[g][e] = v;
        }
    if (lane < 16) {
#pragma unroll
        for (int g = 0; g < kG; ++g) {
            *(float4*)&wacc[w][g * 128 + dg * 8]     = make_float4(acc[g][0], acc[g][1], acc[g][2], acc[g][3]);
            *(float4*)&wacc[w][g * 128 + dg * 8 + 4] = make_float4(acc[g][4], acc[g][5], acc[g][6], acc[g][7]);
        }
        if (lane == 0)
#pragma unroll
            for (int g = 0; g < kG; ++g) { wm[w][g] = m[g]; wl[w][g] = l[g]; }
    }
    __syncthreads();
    {
        const int g = tid >> 7, d = tid & 127;
        float mstar = wm[0][g];
#pragma unroll
        for (int ww = 1; ww < 8; ++ww) mstar = fmaxf(mstar, wm[ww][g]);
        float numer = 0.f, denom = 0.f;
#pragma unroll
        for (int ww = 0; ww < 8; ++ww) {
            float sc = exp2f(wm[ww][g] - mstar);
            denom = fmaf(sc, wl[ww][g], denom);
            numer = fmaf(sc, wacc[ww][g * 128 + d], numer);
        }
        out[(size_t)b * 4096 + h * 512 + g * 128 + d] = numer / denom;
    }
}

extern "C" void kernel_launch(void* const* d_in, const int* in_sizes, int n_in,
                              void* d_out, int out_size, void* d_ws, size_t ws_size,
                              hipStream_t stream) {
    const float* q  = (const float*)d_in[0];
    const float* kv = (const float*)d_in[1];
    const int* sp0 = (const int*)d_in[2];
    const int* sp1 = (const int*)d_in[3];
    const int* sp2 = (const int*)d_in[4];
    float* out = (float*)d_out;
    float* ws = (float*)d_ws;
    if (ws_size >= kWsFloats * sizeof(float)) {
        hipLaunchKernelGGL(l0_kernel,    dim3(512),  dim3(512), 0, stream, q, kv, sp0, ws);
        hipLaunchKernelGGL(seq_kernel,   dim3(1536), dim3(256), 0, stream, q, kv, sp1, sp2, ws);
        hipLaunchKernelGGL(merge_kernel, dim3(1024), dim3(128), 0, stream, ws, out);
    } else {
        hipLaunchKernelGGL(fallback_kernel, dim3(256), dim3(512), 0, stream,
                           q, kv, sp0, sp1, sp2, out);
    }
}